// Round 2
// baseline (1248.190 us; speedup 1.0000x reference)
//
#include <hip/hip_runtime.h>

#define HL 16
#define TBITS 19
#define TMASK ((1u << TBITS) - 1u)
#define HPRIME 2654435761u

// g[l] = fl32(1.0f / res[l]) — compile-time IEEE division matches XLA's
// grid = (bmax-bmin)/res exactly. res = floor(16 * 2^(l/3)).
__constant__ float c_g[HL] = {
    1.0f / 16.0f,  1.0f / 20.0f,  1.0f / 25.0f,  1.0f / 32.0f,
    1.0f / 40.0f,  1.0f / 50.0f,  1.0f / 64.0f,  1.0f / 80.0f,
    1.0f / 101.0f, 1.0f / 128.0f, 1.0f / 161.0f, 1.0f / 203.0f,
    1.0f / 256.0f, 1.0f / 322.0f, 1.0f / 406.0f, 1.0f / 512.0f};

// thread <-> (point n, level l): tid = n*16 + l.
// Each thread: 3 planes x 4 corner gathers (float2), bilinear, 6 f32 out.
// All 12 gather indices are computed first and the 12 loads issued
// back-to-back for maximum memory-level parallelism.
__global__ __launch_bounds__(256) void hash_tri_kernel(
    const float* __restrict__ x, const float* __restrict__ emb,
    float* __restrict__ out, int npts) {
  int tid = blockIdx.x * 256 + threadIdx.x;
  int n = tid >> 4;
  int l = tid & 15;
  if (n >= npts) return;

  float g = c_g[l];
  const float* xp = x + (size_t)n * 3;
  float xv0 = xp[0], xv1 = xp[1], xv2 = xp[2];

  // subtable base for (p=0, level l), in float2 units
  const float2* tabL = (const float2*)emb + ((size_t)l << TBITS);

  float w0s[3], w1s[3];
  unsigned off[12];  // float2-unit offsets into tabL for 3 planes x 4 corners

#pragma unroll
  for (int p = 0; p < 3; ++p) {
    // PLANE_AXES = {(0,1),(0,2),(1,2)}
    float xa = (p == 2) ? xv1 : xv0;
    float xb = (p == 0) ? xv1 : xv2;

    // replicate reference op chain exactly (IEEE div, no fast-math)
    float t0 = xa / g;
    float t1 = xb / g;
    float f0 = floorf(t0);
    float f1 = floorf(t1);
    int b0 = (int)f0;
    int b1 = (int)f1;
    float vm0 = f0 * g;
    float vm1 = f1 * g;
    w0s[p] = (xa - vm0) / g;
    w1s[p] = (xb - vm1) / g;

    // hash2: h = c0 ^ (c1 * PRIME); idx = h & (T-1)
    unsigned k0 = (unsigned)b1 * HPRIME;
    unsigned k1 = k0 + HPRIME;  // (b1+1)*PRIME
    unsigned u0 = (unsigned)b0;
    unsigned u1 = u0 + 1u;

    unsigned pbase = (unsigned)(p * HL) << TBITS;  // plane stride in float2 units
    off[p * 4 + 0] = pbase + ((u0 ^ k0) & TMASK);  // corner (0,0)
    off[p * 4 + 1] = pbase + ((u0 ^ k1) & TMASK);  // corner (0,1)
    off[p * 4 + 2] = pbase + ((u1 ^ k0) & TMASK);  // corner (1,0)
    off[p * 4 + 3] = pbase + ((u1 ^ k1) & TMASK);  // corner (1,1)
  }

  // Issue all 12 gathers back-to-back (MLP), then interpolate.
  float2 v[12];
#pragma unroll
  for (int i = 0; i < 12; ++i) v[i] = tabL[off[i]];

  float2* ob = (float2*)(out + (size_t)n * 96 + l * 6);
#pragma unroll
  for (int p = 0; p < 3; ++p) {
    float w0 = w0s[p], w1 = w1s[p];
    float om0 = 1.0f - w0;
    float om1 = 1.0f - w1;
    float2 v00 = v[p * 4 + 0], v01 = v[p * 4 + 1];
    float2 v10 = v[p * 4 + 2], v11 = v[p * 4 + 3];
    float c0x = v00.x * om0 + v10.x * w0;
    float c0y = v00.y * om0 + v10.y * w0;
    float c1x = v01.x * om0 + v11.x * w0;
    float c1y = v01.y * om0 + v11.y * w0;
    float2 r;
    r.x = c0x * om1 + c1x * w1;
    r.y = c0y * om1 + c1y * w1;
    ob[p] = r;  // out[n*96 + l*6 + p*2 + {0,1}]
  }
}

extern "C" void kernel_launch(void* const* d_in, const int* in_sizes, int n_in,
                              void* d_out, int out_size, void* d_ws,
                              size_t ws_size, hipStream_t stream) {
  const float* x = (const float*)d_in[0];
  const float* emb = (const float*)d_in[1];
  float* out = (float*)d_out;
  int npts = in_sizes[0] / 3;
  int total = npts * 16;
  int blocks = (total + 255) / 256;
  hash_tri_kernel<<<blocks, 256, 0, stream>>>(x, emb, out, npts);
}

// Round 4
// 1079.774 us; speedup vs baseline: 1.1560x; 1.1560x over previous
//
#include <hip/hip_runtime.h>

#define HL 16
#define TBITS 19
#define TMASK ((1u << TBITS) - 1u)
#define HPRIME 2654435761u

// g[l] = fl32(1.0f / res[l]) — compile-time IEEE division matches XLA's
// grid = (bmax-bmin)/res exactly. res = floor(16 * 2^(l/3)).
__constant__ float c_g[HL] = {
    1.0f / 16.0f,  1.0f / 20.0f,  1.0f / 25.0f,  1.0f / 32.0f,
    1.0f / 40.0f,  1.0f / 50.0f,  1.0f / 64.0f,  1.0f / 80.0f,
    1.0f / 101.0f, 1.0f / 128.0f, 1.0f / 161.0f, 1.0f / 203.0f,
    1.0f / 256.0f, 1.0f / 322.0f, 1.0f / 406.0f, 1.0f / 512.0f};

// thread <-> (point n, level l): tid = n*16 + l. Block = 16 points.
// Request-count reduction vs R2:
//  - even-pair trick: u1 = u0^1 when u0 even -> corners (0,c),(1,c) are
//    adjacent table entries -> one aligned float4 load serves both (12->9
//    expected line-requests per thread on the gather side).
//  - output staged in LDS (16 pts x 96 f32 = 6 KB) then written as
//    contiguous float4 (store line-requests ~3x fewer).
__global__ __launch_bounds__(256) void hash_tri_kernel(
    const float* __restrict__ x, const float* __restrict__ emb,
    float* __restrict__ out, int npts) {
  __shared__ float s_out[16 * 96];  // 6 KB per block

  int tid = blockIdx.x * 256 + threadIdx.x;
  int n = tid >> 4;
  int l = tid & 15;
  int ln = threadIdx.x >> 4;  // local point index 0..15

  if (n < npts) {
    float g = c_g[l];
    const float* xp = x + (size_t)n * 3;
    float xv0 = xp[0], xv1 = xp[1], xv2 = xp[2];

    // subtable base for (p=0, level l), in float2 units
    const float2* tabL = (const float2*)emb + ((size_t)l << TBITS);

#pragma unroll
    for (int p = 0; p < 3; ++p) {
      // PLANE_AXES = {(0,1),(0,2),(1,2)}
      float xa = (p == 2) ? xv1 : xv0;
      float xb = (p == 0) ? xv1 : xv2;

      // replicate reference op chain exactly (IEEE div, no fast-math)
      float t0 = xa / g;
      float t1 = xb / g;
      float f0 = floorf(t0);
      float f1 = floorf(t1);
      int b0 = (int)f0;
      int b1 = (int)f1;
      float w0 = (xa - f0 * g) / g;
      float w1 = (xb - f1 * g) / g;

      // hash2: h = c0 ^ (c1 * PRIME); idx = h & (T-1)
      unsigned k0 = (unsigned)b1 * HPRIME;
      unsigned k1 = k0 + HPRIME;  // (b1+1)*PRIME
      unsigned u0 = (unsigned)b0;
      unsigned i00 = (u0 ^ k0) & TMASK;
      unsigned i01 = (u0 ^ k1) & TMASK;

      const float2* tab = tabL + (((size_t)p * HL) << TBITS);
      float2 v00, v01, v10, v11;
      if ((u0 & 1u) == 0u) {
        // u1 = u0^1 -> i10 = i00^1, i11 = i01^1: each column pair is one
        // aligned float4 (entries 2k,2k+1). 2 requests instead of 4.
        const float4* t4 = (const float4*)tab;
        float4 a = t4[i00 >> 1];
        float4 b = t4[i01 >> 1];
        if (i00 & 1u) {
          v00 = make_float2(a.z, a.w);
          v10 = make_float2(a.x, a.y);
        } else {
          v00 = make_float2(a.x, a.y);
          v10 = make_float2(a.z, a.w);
        }
        if (i01 & 1u) {
          v01 = make_float2(b.z, b.w);
          v11 = make_float2(b.x, b.y);
        } else {
          v01 = make_float2(b.x, b.y);
          v11 = make_float2(b.z, b.w);
        }
      } else {
        unsigned u1 = u0 + 1u;
        v00 = tab[i00];
        v01 = tab[i01];
        v10 = tab[(u1 ^ k0) & TMASK];
        v11 = tab[(u1 ^ k1) & TMASK];
      }

      float om0 = 1.0f - w0;
      float om1 = 1.0f - w1;
      float c0x = v00.x * om0 + v10.x * w0;
      float c0y = v00.y * om0 + v10.y * w0;
      float c1x = v01.x * om0 + v11.x * w0;
      float c1y = v01.y * om0 + v11.y * w0;
      int sb = ln * 96 + l * 6 + p * 2;
      s_out[sb + 0] = c0x * om1 + c1x * w1;
      s_out[sb + 1] = c0y * om1 + c1y * w1;
    }
  }
  __syncthreads();

  // Coalesced block store: 16 points * 96 f32 = 384 float4, contiguous.
  const float4* sf4 = (const float4*)s_out;
  float4* of4 = (float4*)out;
  size_t nf4 = (size_t)npts * 24;  // total float4s in out
  size_t gbase = (size_t)blockIdx.x * 384;
  size_t g0 = gbase + threadIdx.x;
  if (g0 < nf4) of4[g0] = sf4[threadIdx.x];
  if (threadIdx.x < 128) {
    size_t g1 = gbase + 256 + threadIdx.x;
    if (g1 < nf4) of4[g1] = sf4[256 + threadIdx.x];
  }
}

extern "C" void kernel_launch(void* const* d_in, const int* in_sizes, int n_in,
                              void* d_out, int out_size, void* d_ws,
                              size_t ws_size, hipStream_t stream) {
  const float* x = (const float*)d_in[0];
  const float* emb = (const float*)d_in[1];
  float* out = (float*)d_out;
  int npts = in_sizes[0] / 3;
  int total = npts * 16;
  int blocks = (total + 255) / 256;
  hash_tri_kernel<<<blocks, 256, 0, stream>>>(x, emb, out, npts);
}